// Round 9
// baseline (169.524 us; speedup 1.0000x reference)
//
#include <hip/hip_runtime.h>
#include <hip/hip_bf16.h>
#include <stdint.h>

#define B_SZ 4
#define T_LEN 8192
#define D_DIM 512
#define M_TOT 32768
#define CHUNK 128
#define NCH 64    // chunks per batch
#define SCS 132   // f32 scan-tile LDS stride: 2-way max (free)

typedef __attribute__((ext_vector_type(8))) short bf16x8v;
typedef __attribute__((ext_vector_type(4))) float f32x4v;

__device__ __forceinline__ unsigned short f2bf(float f) {
  unsigned int u = __float_as_uint(f);
  u += 0x7fffu + ((u >> 16) & 1u);
  return (unsigned short)(u >> 16);
}
__device__ __forceinline__ float bf2f(unsigned short b) {
  return __uint_as_float(((unsigned int)b) << 16);
}
__device__ __forceinline__ float sigmoidf_(float x) { return 1.0f / (1.0f + expf(-x)); }

// async global->LDS, 16B/lane; LDS dest = wave-uniform base + lane*16 (linear)
__device__ __forceinline__ void g2l16(const void* g, void* l) {
  __builtin_amdgcn_global_load_lds((const __attribute__((address_space(1))) void*)g,
                                   (__attribute__((address_space(3))) void*)l, 16, 0, 0);
}

// ---------------------------------------------------------------------------
// prep: blocks 0..1023 -> Wb,Wc to bf16 | block 1024 -> powA[i][ch]=a^(i+1)
//       blocks 1025.. -> x (f32) to bf16 (into d_out scratch region)
__global__ void prep_k(const float* __restrict__ x, const float* __restrict__ Wb,
                       const float* __restrict__ Wc, const float* __restrict__ A,
                       unsigned short* __restrict__ wbf, float* __restrict__ powA,
                       unsigned short* __restrict__ xbf) {
  const int b = blockIdx.x;
  const int tid = threadIdx.x;
  if (b < 1024) {
    int i = b * 256 + tid;
    wbf[i] = f2bf(Wb[i]);
    wbf[262144 + i] = f2bf(Wc[i]);
  } else if (b == 1024) {
#pragma unroll
    for (int s = 0; s < 2; ++s) {
      int ch = s * 256 + tid;
      float a = sigmoidf_(A[ch]);
      float p = a;
      for (int i = 0; i < CHUNK; ++i) {
        powA[i * D_DIM + ch] = p;
        p *= a;
      }
    }
  } else {
    size_t idx = ((size_t)(b - 1025) * 256 + tid) * 8;
    float4 v0 = *(const float4*)&x[idx];
    float4 v1 = *(const float4*)&x[idx + 4];
    uint4 o;
    o.x = (unsigned)f2bf(v0.x) | ((unsigned)f2bf(v0.y) << 16);
    o.y = (unsigned)f2bf(v0.z) | ((unsigned)f2bf(v0.w) << 16);
    o.z = (unsigned)f2bf(v1.x) | ((unsigned)f2bf(v1.y) << 16);
    o.w = (unsigned)f2bf(v1.z) | ((unsigned)f2bf(v1.w) << 16);
    *(uint4*)&xbf[idx] = o;
  }
}

// ---------------------------------------------------------------------------
// In-place chunk-carry prefix. grid=B_SZ, block=512.
__global__ void carry_k(const float* __restrict__ A, float* __restrict__ cst) {
  const int ch = threadIdx.x;
  const int bi = blockIdx.x;
  float a = sigmoidf_(A[ch]);
  float p = a;
#pragma unroll
  for (int i = 0; i < 7; ++i) p *= p;  // a^128
  float H = 0.f;
#pragma unroll 8
  for (int c = 0; c < NCH; ++c) {
    size_t off = ((size_t)bi * NCH + c) * D_DIM + ch;
    float lf = cst[off];
    cst[off] = H;
    H = fmaf(p, H, lf);
  }
}

// ---------------------------------------------------------------------------
// fix: h[g*128+t][ch] += powA[t][ch] * carry[g][ch], in place (bf16).
__global__ void fix_k(unsigned short* __restrict__ h, const float* __restrict__ cst,
                      const float* __restrict__ powA) {
  const int g = blockIdx.x;
  const int u = threadIdx.x & 63;
  const int rs = threadIdx.x >> 6;
  float car[8];
  *(float4*)car = *(const float4*)&cst[(size_t)g * D_DIM + u * 8];
  *(float4*)(car + 4) = *(const float4*)&cst[(size_t)g * D_DIM + u * 8 + 4];
#pragma unroll
  for (int p = 0; p < 16; ++p) {
    int row = p * 8 + rs;
    size_t off = ((size_t)g * CHUNK + row) * D_DIM + u * 8;
    uint4 hv = *(const uint4*)&h[off];
    float4 p0 = *(const float4*)&powA[row * D_DIM + u * 8];
    float4 p1 = *(const float4*)&powA[row * D_DIM + u * 8 + 4];
    const unsigned* hw = (const unsigned*)&hv;
    unsigned ow[4];
#pragma unroll
    for (int q = 0; q < 4; ++q) {
      float pa = (q < 2) ? ((q == 0) ? p0.x : p0.z) : ((q == 2) ? p1.x : p1.z);
      float pb = (q < 2) ? ((q == 0) ? p0.y : p0.w) : ((q == 2) ? p1.y : p1.w);
      float o0 = fmaf(pa, car[2 * q], bf2f((unsigned short)(hw[q] & 0xffff)));
      float o1 = fmaf(pb, car[2 * q + 1], bf2f((unsigned short)(hw[q] >> 16)));
      ow[q] = (unsigned)f2bf(o0) | ((unsigned)f2bf(o1) << 16);
    }
    *(uint4*)&h[off] = make_uint4(ow[0], ow[1], ow[2], ow[3]);
  }
}

// ---------------------------------------------------------------------------
// 128x128xBK32 bf16 GEMM; gload_lds staging in fragment order (at BK=32 the
// per-lane source row=l&15, k-oct=l>>4 makes LDS slot == lane: frag reads are
// base+lane*16, conflict-free). Double-buffered with counted vmcnt(4); 16 KB
// staging per K-step -> 32 KB dbuf -> 4 blocks/CU (2x TLP vs BK=64).
// Race ledger (r6): WAR = lgkm(0)+sched_barrier+s_barrier before restage;
// RAW = vmcnt(4) (own 4 newest = this step's restage stay out) + s_barrier.
// MODE 0: epilogue = fused chunk scan -> h_local bf16 + chunk finals.
// MODE 1: epilogue = per-wave LDS-transposed coalesced f32 C store.
template <int MODE>
__global__ __launch_bounds__(256, 4) void gemm_k(
    const unsigned short* __restrict__ Abf, const unsigned short* __restrict__ Bw,
    float* __restrict__ C, const float* __restrict__ Ad,
    unsigned short* __restrict__ hOut, float* __restrict__ cst) {
  __shared__ union {
    unsigned short st[2][2][4096];  // [buf][A,B] 8 segs x 512 shorts (32 KB)
    float sc[64 * SCS];             // MODE0 scan half-tile (33.8 KB)
    float tp[4][16 * 68];           // MODE1 per-wave transpose
  } sm;

  const int tid = threadIdx.x;
  const int lane = tid & 63;
  const int w = tid >> 6;
  const int wm = (w >> 1) * 64;
  const int wn = (w & 1) * 64;

  // bijective XCD swizzle (grid 1024 = 8*128), n-major within XCD
  const int flat = blockIdx.y * 4 + blockIdx.x;
  const int work = ((flat & 7) << 7) | (flat >> 3);
  const int mt = work >> 2;
  const int bm = mt * 128;
  const int bn = (work & 3) * 128;

  const int l15 = lane & 15;
  const int g4 = lane >> 4;

  // per-lane fragment-order sources: seg covers 16 rows x 32 k; lane l carries
  // (row=l&15, k-oct=l>>4) -> LDS slot l -> frag ds_read = base + lane*16.
  const unsigned short* aSrc[2];
  const unsigned short* bSrc[2];
#pragma unroll
  for (int q = 0; q < 2; ++q) {
    int seg = w * 2 + q;
    aSrc[q] = Abf + (size_t)(bm + seg * 16 + l15) * 512 + g4 * 8;
    bSrc[q] = Bw + (size_t)(bn + seg * 16 + l15) * 512 + g4 * 8;
  }

  auto stage = [&](int buf, int k0) {
#pragma unroll
    for (int q = 0; q < 2; ++q) {
      int seg = w * 2 + q;  // wave-uniform LDS segment
      g2l16(aSrc[q] + k0, &sm.st[buf][0][seg * 512]);
      g2l16(bSrc[q] + k0, &sm.st[buf][1][seg * 512]);
    }
  };

  f32x4v acc[4][4] = {};

  // prologue: fill both buffers; wait only for buf0's 4 (newest 4 stay out)
  stage(0, 0);
  stage(1, 32);
  asm volatile("s_waitcnt vmcnt(4)" ::: "memory");
  __builtin_amdgcn_s_barrier();

#pragma unroll
  for (int t = 0; t < 16; ++t) {
    const int cur = t & 1;
    // #1 read the 8 fragments of buf[cur] (conflict-free: addr = base+lane*16)
    bf16x8v af[4], bf_[4];
#pragma unroll
    for (int i = 0; i < 4; ++i)
      af[i] = *(const bf16x8v*)&sm.st[cur][0][(((w >> 1) * 4) + i) * 512 + lane * 8];
#pragma unroll
    for (int j = 0; j < 4; ++j)
      bf_[j] = *(const bf16x8v*)&sm.st[cur][1][(((w & 1) * 4) + j) * 512 + lane * 8];
    // #2 own reads landed; #3 all waves' reads landed (WAR gate)
    asm volatile("s_waitcnt lgkmcnt(0)" ::: "memory");
    __builtin_amdgcn_sched_barrier(0);
    __builtin_amdgcn_s_barrier();
    // #4 restage just-read buffer with tile t+2 (flies through next step)
    if (t < 14) stage(cur, (t + 2) * 32);
    // #5 MFMA cluster
    __builtin_amdgcn_s_setprio(1);
#pragma unroll
    for (int i = 0; i < 4; ++i)
#pragma unroll
      for (int j = 0; j < 4; ++j)
        acc[i][j] = __builtin_amdgcn_mfma_f32_16x16x32_bf16(af[i], bf_[j], acc[i][j], 0, 0, 0);
    __builtin_amdgcn_s_setprio(0);
    // #6 make buf[cur^1] ready: counted wait (4 newest = our restage stay out)
    if (t < 14) {
      asm volatile("s_waitcnt vmcnt(4)" ::: "memory");
      __builtin_amdgcn_s_barrier();
    } else if (t == 14) {
      asm volatile("s_waitcnt vmcnt(0)" ::: "memory");
      __builtin_amdgcn_s_barrier();
    }
  }

  if constexpr (MODE == 0) {
    // fused chunk-local scan, two 64-row halves
    float a = 0.f, hcar = 0.f;
    if (tid < 128) a = sigmoidf_(Ad[bn + tid]);
#pragma unroll
    for (int half = 0; half < 2; ++half) {
      if ((w >> 1) == half) {
#pragma unroll
        for (int i = 0; i < 4; ++i)
#pragma unroll
          for (int j = 0; j < 4; ++j)
#pragma unroll
            for (int r = 0; r < 4; ++r)
              sm.sc[(i * 16 + g4 * 4 + r) * SCS + wn + j * 16 + l15] = acc[i][j][r];
      }
      __syncthreads();
      if (tid < 128) {
        float h = hcar;
#pragma unroll 8
        for (int t = 0; t < 64; ++t) {
          h = fmaf(a, h, sm.sc[t * SCS + tid]);
          sm.sc[t * SCS + tid] = h;
        }
        hcar = h;
      }
      __syncthreads();
#pragma unroll
      for (int p = 0; p < 4; ++p) {
        int uu = p * 256 + tid;
        int row = uu >> 4, c8 = (uu & 15) * 8;
        const float* s = &sm.sc[row * SCS + c8];
        unsigned w0 = (unsigned)f2bf(s[0]) | ((unsigned)f2bf(s[1]) << 16);
        unsigned w1 = (unsigned)f2bf(s[2]) | ((unsigned)f2bf(s[3]) << 16);
        unsigned w2 = (unsigned)f2bf(s[4]) | ((unsigned)f2bf(s[5]) << 16);
        unsigned w3 = (unsigned)f2bf(s[6]) | ((unsigned)f2bf(s[7]) << 16);
        *(uint4*)&hOut[(size_t)(bm + half * 64 + row) * D_DIM + bn + c8] =
            make_uint4(w0, w1, w2, w3);
      }
      __syncthreads();
    }
    if (tid < 128) cst[(size_t)mt * D_DIM + bn + tid] = hcar;
  } else {
    // coalesced C store via per-wave LDS transpose
    float* tp = sm.tp[w];
#pragma unroll
    for (int i = 0; i < 4; ++i) {
#pragma unroll
      for (int j = 0; j < 4; ++j)
#pragma unroll
        for (int r = 0; r < 4; ++r)
          tp[(g4 * 4 + r) * 68 + j * 16 + l15] = acc[i][j][r];
#pragma unroll
      for (int p = 0; p < 4; ++p) {
        f32x4v v = *(const f32x4v*)&tp[(p * 4 + g4) * 68 + l15 * 4];
        *(f32x4v*)&C[(size_t)(bm + wm + i * 16 + p * 4 + g4) * 512 + bn + wn + l15 * 4] = v;
      }
    }
  }
}

// ---------------------------------------------------------------------------
extern "C" void kernel_launch(void* const* d_in, const int* in_sizes, int n_in,
                              void* d_out, int out_size, void* d_ws, size_t ws_size,
                              hipStream_t stream) {
  const float* x = (const float*)d_in[0];
  const float* W_B = (const float*)d_in[1];
  const float* W_C = (const float*)d_in[2];
  const float* A = (const float*)d_in[3];
  float* out = (float*)d_out;
  char* ws = (char*)d_ws;

  // ws: [0,512K) Wb | [512K,1M) Wc | [1M,1.25M) powA | [1.25M,1.75M) cst |
  //     [2M,34M) h_local bf16.  x_bf16 lives in d_out (dead before GEMM2's C-write).
  unsigned short* Wb = (unsigned short*)ws;
  unsigned short* Wc = Wb + 262144;
  float* powA = (float*)(ws + 0x100000);
  float* cst = (float*)(ws + 0x140000);
  unsigned short* hbf = (unsigned short*)(ws + 0x200000);
  unsigned short* xbf = (unsigned short*)d_out;

  prep_k<<<1025 + 8192, 256, 0, stream>>>(x, W_B, W_C, A, Wb, powA, xbf);

  dim3 gg(D_DIM / 128, M_TOT / 128);  // (4, 256)
  gemm_k<0><<<gg, 256, 0, stream>>>(xbf, Wb, nullptr, A, hbf, cst);
  carry_k<<<B_SZ, 512, 0, stream>>>(A, cst);
  fix_k<<<256, 512, 0, stream>>>(hbf, cst, powA);
  gemm_k<1><<<gg, 256, 0, stream>>>(hbf, Wc, out, A, nullptr, cst);
}

// Round 10
// 153.709 us; speedup vs baseline: 1.1029x; 1.1029x over previous
//
#include <hip/hip_runtime.h>
#include <hip/hip_bf16.h>
#include <stdint.h>

#define B_SZ 4
#define T_LEN 8192
#define D_DIM 512
#define M_TOT 32768
#define CHUNK 256   // scan chunk == GEMM M-tile
#define NCH 32      // chunks per batch
#define NCHG 128    // chunks global
#define SCS2 260    // f32 scan-tile LDS stride

typedef __attribute__((ext_vector_type(8))) short bf16x8v;
typedef __attribute__((ext_vector_type(4))) float f32x4v;

__device__ __forceinline__ unsigned short f2bf(float f) {
  unsigned int u = __float_as_uint(f);
  u += 0x7fffu + ((u >> 16) & 1u);
  return (unsigned short)(u >> 16);
}
__device__ __forceinline__ float bf2f(unsigned short b) {
  return __uint_as_float(((unsigned int)b) << 16);
}
__device__ __forceinline__ float sigmoidf_(float x) { return 1.0f / (1.0f + expf(-x)); }

// async global->LDS, 16B/lane; LDS dest = wave-uniform base + lane*16 (linear)
__device__ __forceinline__ void g2l16(const void* g, void* l) {
  __builtin_amdgcn_global_load_lds((const __attribute__((address_space(1))) void*)g,
                                   (__attribute__((address_space(3))) void*)l, 16, 0, 0);
}

// ---------------------------------------------------------------------------
// prep: blocks 0..1023 -> Wb,Wc to bf16 | block 1024 -> powA[i][ch]=a^(i+1)
//       blocks 1025.. -> x (f32) to bf16 (into d_out scratch region)
__global__ void prep_k(const float* __restrict__ x, const float* __restrict__ Wb,
                       const float* __restrict__ Wc, const float* __restrict__ A,
                       unsigned short* __restrict__ wbf, float* __restrict__ powA,
                       unsigned short* __restrict__ xbf) {
  const int b = blockIdx.x;
  const int tid = threadIdx.x;
  if (b < 1024) {
    int i = b * 256 + tid;
    wbf[i] = f2bf(Wb[i]);
    wbf[262144 + i] = f2bf(Wc[i]);
  } else if (b == 1024) {
#pragma unroll
    for (int s = 0; s < 2; ++s) {
      int ch = s * 256 + tid;
      float a = sigmoidf_(A[ch]);
      float p = a;
      for (int i = 0; i < CHUNK; ++i) {
        powA[i * D_DIM + ch] = p;
        p *= a;
      }
    }
  } else {
    size_t idx = ((size_t)(b - 1025) * 256 + tid) * 8;
    float4 v0 = *(const float4*)&x[idx];
    float4 v1 = *(const float4*)&x[idx + 4];
    uint4 o;
    o.x = (unsigned)f2bf(v0.x) | ((unsigned)f2bf(v0.y) << 16);
    o.y = (unsigned)f2bf(v0.z) | ((unsigned)f2bf(v0.w) << 16);
    o.z = (unsigned)f2bf(v1.x) | ((unsigned)f2bf(v1.y) << 16);
    o.w = (unsigned)f2bf(v1.z) | ((unsigned)f2bf(v1.w) << 16);
    *(uint4*)&xbf[idx] = o;
  }
}

// ---------------------------------------------------------------------------
// In-place chunk-carry prefix over 256-row chunks. grid=B_SZ, block=512.
__global__ void carry_k(const float* __restrict__ A, float* __restrict__ cst) {
  const int ch = threadIdx.x;
  const int bi = blockIdx.x;
  float a = sigmoidf_(A[ch]);
  float p = a;
#pragma unroll
  for (int i = 0; i < 8; ++i) p *= p;  // a^256
  float H = 0.f;
#pragma unroll 8
  for (int c = 0; c < NCH; ++c) {
    size_t off = ((size_t)bi * NCH + c) * D_DIM + ch;
    float lf = cst[off];
    cst[off] = H;
    H = fmaf(p, H, lf);
  }
}

// ---------------------------------------------------------------------------
// fix: h[g*256+t][ch] += powA[t][ch] * carry[g][ch], in place (bf16).
// grid = 128 chunks, block = 512.
__global__ void fix_k(unsigned short* __restrict__ h, const float* __restrict__ cst,
                      const float* __restrict__ powA) {
  const int g = blockIdx.x;
  const int u = threadIdx.x & 63;
  const int rs = threadIdx.x >> 6;
  float car[8];
  *(float4*)car = *(const float4*)&cst[(size_t)g * D_DIM + u * 8];
  *(float4*)(car + 4) = *(const float4*)&cst[(size_t)g * D_DIM + u * 8 + 4];
#pragma unroll
  for (int p = 0; p < 32; ++p) {
    int row = p * 8 + rs;
    size_t off = ((size_t)g * CHUNK + row) * D_DIM + u * 8;
    uint4 hv = *(const uint4*)&h[off];
    float4 p0 = *(const float4*)&powA[row * D_DIM + u * 8];
    float4 p1 = *(const float4*)&powA[row * D_DIM + u * 8 + 4];
    const unsigned* hw = (const unsigned*)&hv;
    unsigned ow[4];
#pragma unroll
    for (int q = 0; q < 4; ++q) {
      float pa = (q < 2) ? ((q == 0) ? p0.x : p0.z) : ((q == 2) ? p1.x : p1.z);
      float pb = (q < 2) ? ((q == 0) ? p0.y : p0.w) : ((q == 2) ? p1.y : p1.w);
      float o0 = fmaf(pa, car[2 * q], bf2f((unsigned short)(hw[q] & 0xffff)));
      float o1 = fmaf(pb, car[2 * q + 1], bf2f((unsigned short)(hw[q] >> 16)));
      ow[q] = (unsigned)f2bf(o0) | ((unsigned)f2bf(o1) << 16);
    }
    *(uint4*)&h[off] = make_uint4(ow[0], ow[1], ow[2], ow[3]);
  }
}

// ---------------------------------------------------------------------------
// 256x256xBK64 bf16 GEMM, 8 waves (2M x 4N), 128x64 per wave, 1 block/CU.
// Frag-order gload_lds staging (seg = 16 rows x 32 k, lane l -> row l&15,
// k-oct l>>4 -> frag ds_read = base + lane*16, conflict-free). Double-buffered
// counted vmcnt(8). Race ledger (r6): WAR = lgkm(0)+sched_barrier+s_barrier
// covering ALL reads of buf[cur] before restage; RAW = vmcnt(8)+s_barrier.
// MODE 0: epilogue = fused 256-row chunk scan -> h_local bf16 + chunk finals.
// MODE 1: epilogue = per-wave LDS-transposed coalesced f32 C store.
template <int MODE>
__global__ __launch_bounds__(512, 2) void gemm_k(
    const unsigned short* __restrict__ Abf, const unsigned short* __restrict__ Bw,
    float* __restrict__ C, const float* __restrict__ Ad,
    unsigned short* __restrict__ hOut, float* __restrict__ cst) {
  __shared__ union {
    unsigned short st[2][2][32 * 512];  // [buf][A,B] 32 segs x 1KB (128 KB)
    float sc[64 * SCS2];                // MODE0 scan quarter-tile (66.6 KB)
    float tp[8][16 * 68];               // MODE1 per-wave transpose (69.6 KB)
  } sm;

  const int tid = threadIdx.x;
  const int lane = tid & 63;
  const int w = tid >> 6;          // 0..7
  const int wmi = w >> 2;          // wave M index (0..1) -> 128-row half
  const int wni = w & 3;           // wave N index (0..3) -> 64-col slice
  const int wn = wni * 64;

  // bijective XCD swizzle (grid 256 = 8*32); work = mt*2 + ntile
  const int flat = blockIdx.y * 2 + blockIdx.x;
  const int work = ((flat & 7) << 5) | (flat >> 3);
  const int mt = work >> 1;        // M-tile == scan chunk id (0..127)
  const int bm = mt * 256;
  const int bn = (work & 1) * 256;

  const int l15 = lane & 15;
  const int g4 = lane >> 4;

  // per-lane frag-order sources; wave w stages segs w*4..w*4+3 of A and B
  const unsigned short* aS[4];
  const unsigned short* bS[4];
#pragma unroll
  for (int q = 0; q < 4; ++q) {
    int seg = w * 4 + q;
    int rg = seg >> 1, kh = seg & 1;
    aS[q] = Abf + (size_t)(bm + rg * 16 + l15) * 512 + kh * 32 + g4 * 8;
    bS[q] = Bw + (size_t)(bn + rg * 16 + l15) * 512 + kh * 32 + g4 * 8;
  }

  auto stage = [&](int buf, int k0) {
#pragma unroll
    for (int q = 0; q < 4; ++q) {
      int seg = w * 4 + q;  // wave-uniform LDS segment
      g2l16(aS[q] + k0, &sm.st[buf][0][seg * 512]);
      g2l16(bS[q] + k0, &sm.st[buf][1][seg * 512]);
    }
  };

  f32x4v acc[8][4] = {};

  // prologue: fill both buffers; wait only buf0's 8 (newest 8 stay in flight)
  stage(0, 0);
  stage(1, 64);
  asm volatile("s_waitcnt vmcnt(8)" ::: "memory");
  __builtin_amdgcn_s_barrier();

#pragma unroll
  for (int t = 0; t < 8; ++t) {
    const int cur = t & 1;
#pragma unroll
    for (int ks = 0; ks < 2; ++ks) {
      bf16x8v af[8], bf_[4];
#pragma unroll
      for (int i = 0; i < 8; ++i)
        af[i] = *(const bf16x8v*)&sm.st[cur][0][((wmi * 8 + i) * 2 + ks) * 512 + lane * 8];
#pragma unroll
      for (int j = 0; j < 4; ++j)
        bf_[j] = *(const bf16x8v*)&sm.st[cur][1][((wni * 4 + j) * 2 + ks) * 512 + lane * 8];
      if (ks == 1) {
        // WAR gate: all reads of buf[cur] (ks0 drained earlier in-order) done
        asm volatile("s_waitcnt lgkmcnt(0)" ::: "memory");
        __builtin_amdgcn_sched_barrier(0);
        __builtin_amdgcn_s_barrier();
        if (t < 6) stage(cur, (t + 2) * 64);  // restage flies through next step
      }
      __builtin_amdgcn_s_setprio(1);
#pragma unroll
      for (int i = 0; i < 8; ++i)
#pragma unroll
        for (int j = 0; j < 4; ++j)
          acc[i][j] = __builtin_amdgcn_mfma_f32_16x16x32_bf16(af[i], bf_[j], acc[i][j], 0, 0, 0);
      __builtin_amdgcn_s_setprio(0);
    }
    // RAW gate for buf[cur^1]: counted wait (8 newest = our restage stay out)
    if (t < 6) {
      asm volatile("s_waitcnt vmcnt(8)" ::: "memory");
      __builtin_amdgcn_s_barrier();
    } else if (t == 6) {
      asm volatile("s_waitcnt vmcnt(0)" ::: "memory");
      __builtin_amdgcn_s_barrier();
    }
  }

  if constexpr (MODE == 0) {
    // fused 256-row chunk scan, four 64-row quarters; 256 channels/block-half
    float a = 0.f, hcar = 0.f;
    if (tid < 256) a = sigmoidf_(Ad[bn + tid]);
#pragma unroll
    for (int q = 0; q < 4; ++q) {
      if (wmi == (q >> 1)) {  // waves owning these 64 rows scatter acc
        int i0 = (q & 1) * 4;
#pragma unroll
        for (int ii = 0; ii < 4; ++ii)
#pragma unroll
          for (int j = 0; j < 4; ++j)
#pragma unroll
            for (int r = 0; r < 4; ++r)
              sm.sc[(ii * 16 + g4 * 4 + r) * SCS2 + wn + j * 16 + l15] = acc[i0 + ii][j][r];
      }
      __syncthreads();
      if (tid < 256) {
        float h = hcar;
#pragma unroll 8
        for (int tt = 0; tt < 64; ++tt) {
          h = fmaf(a, h, sm.sc[tt * SCS2 + tid]);
          sm.sc[tt * SCS2 + tid] = h;
        }
        hcar = h;
      }
      __syncthreads();
      // write this quarter's 64 rows x 256 ch as bf16 (coalesced uint4)
#pragma unroll
      for (int p = 0; p < 4; ++p) {
        int uu = p * 512 + tid;
        int row = uu >> 5, c8 = (uu & 31) * 8;
        const float* s = &sm.sc[row * SCS2 + c8];
        unsigned w0 = (unsigned)f2bf(s[0]) | ((unsigned)f2bf(s[1]) << 16);
        unsigned w1 = (unsigned)f2bf(s[2]) | ((unsigned)f2bf(s[3]) << 16);
        unsigned w2 = (unsigned)f2bf(s[4]) | ((unsigned)f2bf(s[5]) << 16);
        unsigned w3 = (unsigned)f2bf(s[6]) | ((unsigned)f2bf(s[7]) << 16);
        *(uint4*)&hOut[(size_t)(bm + q * 64 + row) * D_DIM + bn + c8] =
            make_uint4(w0, w1, w2, w3);
      }
      __syncthreads();
    }
    if (tid < 256) cst[(size_t)mt * D_DIM + bn + tid] = hcar;  // chunk-local final
  } else {
    // coalesced C store via per-wave LDS transpose (16x68 region per wave)
    float* tp = sm.tp[w];
#pragma unroll
    for (int i = 0; i < 8; ++i) {
#pragma unroll
      for (int j = 0; j < 4; ++j)
#pragma unroll
        for (int r = 0; r < 4; ++r)
          tp[(g4 * 4 + r) * 68 + j * 16 + l15] = acc[i][j][r];
#pragma unroll
      for (int p = 0; p < 4; ++p) {
        f32x4v v = *(const f32x4v*)&tp[(p * 4 + g4) * 68 + l15 * 4];
        *(f32x4v*)&C[(size_t)(bm + wmi * 128 + i * 16 + p * 4 + g4) * 512 + bn + wn + l15 * 4] = v;
      }
    }
  }
}

// ---------------------------------------------------------------------------
extern "C" void kernel_launch(void* const* d_in, const int* in_sizes, int n_in,
                              void* d_out, int out_size, void* d_ws, size_t ws_size,
                              hipStream_t stream) {
  const float* x = (const float*)d_in[0];
  const float* W_B = (const float*)d_in[1];
  const float* W_C = (const float*)d_in[2];
  const float* A = (const float*)d_in[3];
  float* out = (float*)d_out;
  char* ws = (char*)d_ws;

  // ws: [0,512K) Wb | [512K,1M) Wc | [1M,1.5M) powA[256][512] f32 |
  //     [1.5M,1.75M) cst[128][512] f32 | [2M,34M) h_local bf16.
  // x_bf16 lives in d_out (dead before GEMM2's C-write).
  unsigned short* Wb = (unsigned short*)ws;
  unsigned short* Wc = Wb + 262144;
  float* powA = (float*)(ws + 0x100000);
  float* cst = (float*)(ws + 0x180000);
  unsigned short* hbf = (unsigned short*)(ws + 0x200000);
  unsigned short* xbf = (unsigned short*)d_out;

  prep_k<<<1025 + 8192, 256, 0, stream>>>(x, W_B, W_C, A, Wb, powA, xbf);

  dim3 gg(2, 128);  // 256 blocks = 1/CU
  gemm_k<0><<<gg, 512, 0, stream>>>(xbf, Wb, nullptr, A, hbf, cst);
  carry_k<<<B_SZ, 512, 0, stream>>>(A, cst);
  fix_k<<<NCHG, 512, 0, stream>>>(hbf, cst, powA);
  gemm_k<1><<<gg, 512, 0, stream>>>(hbf, Wc, out, A, nullptr, cst);
}